// Round 17
// baseline (155.976 us; speedup 1.0000x reference)
//
#include <hip/hip_runtime.h>
#include <cstdint>
#include <cstddef>

typedef unsigned short u16;
typedef float f32x4 __attribute__((ext_vector_type(4)));
typedef short short8 __attribute__((ext_vector_type(8)));
typedef u16 u16x4 __attribute__((ext_vector_type(4)));
typedef unsigned u32x2 __attribute__((ext_vector_type(2)));

// D = A*B + C  (16x16x32 bf16, fp32 acc).  A-frag: row=lane&15, k=(lane>>4)*8+e
// B-frag: col=lane&15, k=(lane>>4)*8+e.   C/D: col=lane&15, row=(lane>>4)*4+reg.
// The ONLY MFMA shape verified on this chip in this session; 16x16x16 NaNs,
// 32x32x16 produced finite-wrong output twice (rounds 7/8) — both banned.
// Round-11 lesson: __launch_bounds__ min-waves + register hoists => 64-VGPR cap
// => scratch spill.  No min-waves clause anywhere.
#define MFMA_BF16(acc, a, b) \
  asm("v_mfma_f32_16x16x32_bf16 %0, %1, %2, %0" : "+v"(acc) : "v"(a), "v"(b))

// packed f32x2 -> bf16x2 (RNE; bit-identical to manual RNE — rounds 6/15 evidence)
#define CVT_PK(w, lo, hi) \
  asm("v_cvt_pk_bf16_f32 %0, %1, %2" : "=v"(w) : "v"(lo), "v"(hi))

// async global->LDS, 16B per lane; LDS dest = wave-uniform base + lane*16
#define GLDS16(gp, lp) __builtin_amdgcn_global_load_lds( \
    (__attribute__((address_space(1))) void*)(void*)(uintptr_t)(gp), \
    (__attribute__((address_space(3))) void*)(lp), 16, 0, 0)

static __device__ __forceinline__ u16 f2bf(float f) {
  union { float f; unsigned u; } x; x.f = f;
  unsigned u = x.u + 0x7fffu + ((x.u >> 16) & 1u);
  return (u16)(u >> 16);
}
static __device__ __forceinline__ float bf2f(u16 h) {
  union { unsigned u; float f; } x; x.u = (unsigned)h << 16; return x.f;
}

// ---------------- fused prep ----------------
// blocks [0,4096): x f32->bf16
// [4096,4288): Wqkv transpose (24x8), q-cols pre-scaled by 0.125
// [4288,4352): Wo transpose (8x8), rows pre-scaled by ln_g  ->  wgT[j][k]=g[k]Wo[k][j]
// [4352,4354): Sg[j] = sum_k bf16(g_k*Wo_kj);  c2[j] = sum_k b_k*Wo_kj + bo_j
__global__ __launch_bounds__(256) void prep_kernel(const float* __restrict__ x,
                                                   u16* __restrict__ xbf,
                                                   const float* __restrict__ Wqkv,
                                                   u16* __restrict__ wqkvt,
                                                   const float* __restrict__ Wo,
                                                   u16* __restrict__ wgt,
                                                   const float* __restrict__ g,
                                                   const float* __restrict__ bvec,
                                                   const float* __restrict__ bo,
                                                   float* __restrict__ Sg,
                                                   float* __restrict__ c2) {
  __shared__ float tile[64][65];
  const int bid = blockIdx.x, tid = threadIdx.x;
  if (bid < 4096) {
    for (int i = bid * 256 + tid; i < 2097152; i += 4096 * 256) {
      f32x4 v = ((const f32x4*)x)[i];
      u16x4 o;
      o[0] = f2bf(v[0]); o[1] = f2bf(v[1]); o[2] = f2bf(v[2]); o[3] = f2bf(v[3]);
      ((u16x4*)xbf)[i] = o;
    }
    return;
  }
  if (bid < 4288) {                       // Wqkv transpose, 0.125 on q cols
    int t = bid - 4096; int bx = t % 24, by = t / 24;
    int c0 = bx * 64, r0 = by * 64;
    for (int t2 = tid; t2 < 4096; t2 += 256) {
      int r = t2 >> 6, c = t2 & 63;
      tile[r][c] = Wqkv[(size_t)(r0 + r) * 1536 + c0 + c];
    }
    __syncthreads();
    for (int t2 = tid; t2 < 4096; t2 += 256) {
      int rr = t2 >> 6, cc = t2 & 63;
      float sc = (c0 + rr) < 512 ? 0.125f : 1.0f;
      wqkvt[(size_t)(c0 + rr) * 512 + r0 + cc] = f2bf(tile[cc][rr] * sc);
    }
    return;
  }
  if (bid < 4352) {                       // Wo transpose with g row-scale
    int t = bid - 4288; int bx = t & 7, by = t >> 3;
    int c0 = bx * 64, r0 = by * 64;
    for (int t2 = tid; t2 < 4096; t2 += 256) {
      int r = t2 >> 6, c = t2 & 63;
      tile[r][c] = Wo[(size_t)(r0 + r) * 512 + c0 + c];
    }
    __syncthreads();
    for (int t2 = tid; t2 < 4096; t2 += 256) {
      int rr = t2 >> 6, cc = t2 & 63;
      wgt[(size_t)(c0 + rr) * 512 + r0 + cc] = f2bf(tile[cc][rr] * g[r0 + cc]);
    }
    return;
  }
  {                                       // Sg / c2 columns
    int j = (bid - 4352) * 256 + tid;
    float sg = 0.f, cc = 0.f;
    for (int k = 0; k < 512; ++k) {
      float w = Wo[(size_t)k * 512 + j];
      sg += bf2f(f2bf(g[k] * w));         // match MFMA's bf16 quantization of Wg
      cc += bvec[k] * w;
    }
    Sg[j] = sg;
    c2[j] = cc + bo[j];
  }
}

// ---------------- GEMM1: qkv = x_bf16[16384,512] @ WqkvT[1536,512]^T ----------------
// cols 0..1023 -> qk buffer [16384][1024] (q pre-scaled by 0.125 via Wqkv);
// cols 1024..1535 (v) -> vT[b*512+d][1024] via LDS transpose (coalesced writes).
// Grid: 1D 1536, XCD-chunked decode.  Packed cvt_pk epilogues.
__global__ __launch_bounds__(256) void gemm_qkv_kernel(const u16* __restrict__ A,
                                                       const u16* __restrict__ BT,
                                                       u16* __restrict__ qk,
                                                       u16* __restrict__ vT) {
  __shared__ u16 smem[16896];          // 33792 B; As=smem[0:8192], Bs=smem[8192:16384]
  u16* As = smem;
  u16* Bs = smem + 8192;
  const int tid = threadIdx.x, lane = tid & 63, wave = tid >> 6;
  const int wr = wave >> 1, wc = wave & 1;
  const int bid = blockIdx.x;
  const int lin = (bid & 7) * 192 + (bid >> 3);        // bijective: 1536 % 8 == 0
  const int my = lin / 12, nx = lin - my * 12;
  const int m0 = my * 128, n0 = nx * 128;
  f32x4 acc[4][4] = {};
  for (int kt = 0; kt < 8; ++kt) {
    int k0 = kt * 64;
    __syncthreads();
    #pragma unroll
    for (int t = 0; t < 4; ++t) {
      int ch = wave * 4 + t;
      GLDS16(A + (size_t)(m0 + ch * 8 + (lane >> 3)) * 512 + k0 + (lane & 7) * 8, &As[ch * 512]);
      GLDS16(BT + (size_t)(n0 + ch * 8 + (lane >> 3)) * 512 + k0 + (lane & 7) * 8, &Bs[ch * 512]);
    }
    __syncthreads();
    #pragma unroll
    for (int kk = 0; kk < 2; ++kk) {
      short8 af[4], bfr[4];
      #pragma unroll
      for (int m = 0; m < 4; ++m)
        af[m] = *(const short8*)&As[(wr * 64 + m * 16 + (lane & 15)) * 64 + kk * 32 + (lane >> 4) * 8];
      #pragma unroll
      for (int n = 0; n < 4; ++n)
        bfr[n] = *(const short8*)&Bs[(wc * 64 + n * 16 + (lane & 15)) * 64 + kk * 32 + (lane >> 4) * 8];
      #pragma unroll
      for (int m = 0; m < 4; ++m)
        #pragma unroll
        for (int n = 0; n < 4; ++n)
          MFMA_BF16(acc[m][n], af[m], bfr[n]);
    }
  }
  const int row0 = m0 + wr * 64, col0 = n0 + wc * 64;
  if (n0 < 1024) {
    #pragma unroll
    for (int m = 0; m < 4; ++m) {
      int row = row0 + m * 16 + (lane >> 4) * 4;
      #pragma unroll
      for (int n = 0; n < 4; ++n) {
        int col = col0 + n * 16 + (lane & 15);
        unsigned w0, w1;
        CVT_PK(w0, acc[m][n][0], acc[m][n][1]);
        CVT_PK(w1, acc[m][n][2], acc[m][n][3]);
        qk[(size_t)(row + 0) * 1024 + col] = (u16)(w0 & 0xffffu);
        qk[(size_t)(row + 1) * 1024 + col] = (u16)(w0 >> 16);
        qk[(size_t)(row + 2) * 1024 + col] = (u16)(w1 & 0xffffu);
        qk[(size_t)(row + 3) * 1024 + col] = (u16)(w1 >> 16);
      }
    }
  } else {
    // V block: transpose through LDS, then coalesced global writes.
    __syncthreads();                   // all As/Bs reads done; smem reused as Td[128][132]
    const int lo = lane & 15, g = lane >> 4;
    #pragma unroll
    for (int m = 0; m < 4; ++m) {
      int tl0 = wr * 64 + m * 16 + g * 4;          // token_local base (4 consecutive)
      #pragma unroll
      for (int n = 0; n < 4; ++n) {
        int dl = wc * 64 + n * 16 + lo;            // d_local
        u32x2 pk2;
        CVT_PK(pk2[0], acc[m][n][0], acc[m][n][1]);
        CVT_PK(pk2[1], acc[m][n][2], acc[m][n][3]);
        *(u32x2*)&smem[dl * 132 + tl0] = pk2;      // Td[dl][tl0..tl0+3]
      }
    }
    __syncthreads();
    const int bb = m0 >> 10, nn0 = m0 & 1023, d0 = n0 - 1024;
    for (int t = tid; t < 128 * 32; t += 256) {    // 128 d-rows x 32 8B-segs
      int d = t >> 5, sg = t & 31;
      u16x4 v = *(const u16x4*)&smem[d * 132 + sg * 4];
      *(u16x4*)&vT[(size_t)(bb * 512 + d0 + d) * 1024 + nn0 + sg * 4] = v;
    }
  }
}

// ---------------- attention: O = relu(Q K^T) @ V  (scale pre-folded into Q) ----------------
// 2 q-tiles per block (round-14-verified), packed cvt_pk conversions (round-15).
__global__ __launch_bounds__(256) void attn_kernel(const u16* __restrict__ qk,
                                                   const u16* __restrict__ vT,
                                                   u16* __restrict__ aout) {
  __shared__ u16 smem[32768];          // 65536 B
  u16* Ks = smem;                      // [128][64]  bytes 0..16K
  u16* Vs = smem + 8192;               // [64][128]  bytes 16K..32K
  u16* Ss = smem + 16384;              // [128][128] bytes 32K..64K (no aliasing)
  const int tid = threadIdx.x, lane = tid & 63, wave = tid >> 6;
  const int wr = wave >> 1, wc = wave & 1;
  const int L = blockIdx.x;
  const int qt2 = L >> 7, bh = L & 127, h = bh & 7, b = bh >> 3;
  const size_t qrow0 = (size_t)b * 1024 + qt2 * 256;

  short8 qf[2][4][2];
  #pragma unroll
  for (int q = 0; q < 2; ++q)
    #pragma unroll
    for (int m = 0; m < 4; ++m)
      #pragma unroll
      for (int kk = 0; kk < 2; ++kk)
        qf[q][m][kk] = *(const short8*)&qk[(qrow0 + q * 128 + wr * 64 + m * 16 + (lane & 15)) * 1024
                                           + h * 64 + kk * 32 + (lane >> 4) * 8];
  f32x4 acc[2][4][2] = {};
  for (int jt = 0; jt < 8; ++jt) {
    __syncthreads();                                         // prev jt Ks/Vs/Ss reads done
    const u16* Kg = qk + ((size_t)b * 1024 + jt * 128) * 1024 + 512 + h * 64;
    const u16* Vg = vT + ((size_t)b * 512 + h * 64) * 1024 + jt * 128;
    #pragma unroll
    for (int t = 0; t < 4; ++t) {
      int ch = wave * 4 + t;
      GLDS16(Kg + (size_t)(ch * 8 + (lane >> 3)) * 1024 + ((lane & 7) ^ (lane >> 3)) * 8,
             &Ks[ch * 512]);
      GLDS16(Vg + (size_t)(ch * 4 + (lane >> 4)) * 1024 + ((lane & 15) ^ (t * 4 + (lane >> 4))) * 8,
             &Vs[ch * 512]);
    }
    __syncthreads();                                         // K,V staged
    #pragma unroll
    for (int q = 0; q < 2; ++q) {
      // S^T = K.Q^T : sacc[n][m] tile has row=j_local, col=i_local
      f32x4 sacc[4][4] = {};
      __builtin_amdgcn_s_setprio(1);
      #pragma unroll
      for (int kk = 0; kk < 2; ++kk) {
        short8 kf[4];
        #pragma unroll
        for (int n = 0; n < 4; ++n) {
          int r = wc * 64 + n * 16 + (lane & 15);
          int slot = kk * 4 + (lane >> 4);                   // 0..7
          kf[n] = *(const short8*)&Ks[r * 64 + ((slot ^ (r & 7)) * 8)];
        }
        #pragma unroll
        for (int n = 0; n < 4; ++n)
          #pragma unroll
          for (int m = 0; m < 4; ++m)
            MFMA_BF16(sacc[n][m], kf[n], qf[q][m][kk]);
      }
      __builtin_amdgcn_s_setprio(0);
      if (q == 1) __syncthreads();                           // PV(q0) Ss reads done
      // S-write (q==0 needs no pre-barrier: prev Ss readers fenced at loop top)
      #pragma unroll
      for (int m = 0; m < 4; ++m) {
        int i = wr * 64 + m * 16 + (lane & 15);
        unsigned rowbase = (unsigned)i * 256;                // byte offset of S row
        unsigned sw = (unsigned)(i & 15) << 4;
        #pragma unroll
        for (int n = 0; n < 4; ++n) {
          int j0 = wc * 64 + n * 16 + (lane >> 4) * 4;
          float a0 = fmaxf(sacc[n][m][0], 0.f), a1 = fmaxf(sacc[n][m][1], 0.f);
          float a2 = fmaxf(sacc[n][m][2], 0.f), a3 = fmaxf(sacc[n][m][3], 0.f);
          u32x2 pk2;
          CVT_PK(pk2[0], a0, a1);
          CVT_PK(pk2[1], a2, a3);
          *(u32x2*)((char*)Ss + (rowbase + (((unsigned)j0 * 2) ^ sw))) = pk2;
        }
      }
      __syncthreads();                                       // S visible
      __builtin_amdgcn_s_setprio(1);
      #pragma unroll
      for (int ks = 0; ks < 4; ++ks) {
        short8 sa[4], vb[2];
        #pragma unroll
        for (int m = 0; m < 4; ++m) {
          int i = wr * 64 + m * 16 + (lane & 15);
          unsigned c2v = (unsigned)(ks * 32 + (lane >> 4) * 8) * 2;
          sa[m] = *(const short8*)((const char*)Ss + (unsigned)i * 256 + (c2v ^ ((unsigned)(i & 15) << 4)));
        }
        #pragma unroll
        for (int n = 0; n < 2; ++n) {
          int r = wc * 32 + n * 16 + (lane & 15);
          int slot = ks * 4 + (lane >> 4);                   // 0..15
          vb[n] = *(const short8*)&Vs[r * 128 + ((slot ^ (r & 15)) * 8)];
        }
        #pragma unroll
        for (int m = 0; m < 4; ++m)
          #pragma unroll
          for (int n = 0; n < 2; ++n)
            MFMA_BF16(acc[q][m][n], sa[m], vb[n]);
      }
      __builtin_amdgcn_s_setprio(0);
    }
  }
  #pragma unroll
  for (int q = 0; q < 2; ++q)
    #pragma unroll
    for (int m = 0; m < 4; ++m) {
      int row = q * 128 + wr * 64 + m * 16 + (lane >> 4) * 4;
      #pragma unroll
      for (int n = 0; n < 2; ++n) {
        int col = h * 64 + wc * 32 + n * 16 + (lane & 15);
        unsigned w0, w1;
        CVT_PK(w0, acc[q][m][n][0], acc[q][m][n][1]);
        CVT_PK(w1, acc[q][m][n][2], acc[q][m][n][3]);
        aout[(qrow0 + row + 0) * 512 + col] = (u16)(w0 & 0xffffu);
        aout[(qrow0 + row + 1) * 512 + col] = (u16)(w0 >> 16);
        aout[(qrow0 + row + 2) * 512 + col] = (u16)(w1 & 0xffffu);
        aout[(qrow0 + row + 3) * 512 + col] = (u16)(w1 >> 16);
      }
    }
}

// ---------------- GEMM2 + fused LayerNorm ----------------
// out[i,j] = rstd_i*(rawdot[i,j] - mu_i*Sg[j]) + c2[j],  rawdot = att @ wgT^T
// (LN commuted through the GEMM; g folded into wgT, b/bo folded into c2.)
// Stats prologue: 2 threads/row over att rows m0..m0+127 -> mu/rstd in LDS.
// Grid: 1D 512, XCD-chunked decode.
__global__ __launch_bounds__(256) void gemm_out_kernel(const u16* __restrict__ att,
                                                       const u16* __restrict__ BT,
                                                       const float* __restrict__ Sg,
                                                       const float* __restrict__ c2,
                                                       float* __restrict__ out) {
  __shared__ u16 smem[16896];          // As 16KB | Bs 16KB | muL 512B | rsL 512B
  u16* As = smem;
  u16* Bs = smem + 8192;
  float* muL = (float*)&smem[16384];   // [128]
  float* rsL = (float*)&smem[16640];   // [128]
  const int tid = threadIdx.x, lane = tid & 63, wave = tid >> 6;
  const int wr = wave >> 1, wc = wave & 1;
  const int bid = blockIdx.x;
  const int lin = (bid & 7) * 64 + (bid >> 3);
  const int m0 = (lin >> 2) * 128, n0 = (lin & 3) * 128;
  // ---- LN stats for this block's 128 rows ----
  {
    const int r = tid >> 1, half = tid & 1;
    const u16* ar = att + (size_t)(m0 + r) * 512 + half * 256;
    float s = 0.f, q = 0.f;
    #pragma unroll
    for (int i = 0; i < 32; ++i) {
      short8 hv = *(const short8*)&ar[i * 8];
      #pragma unroll
      for (int e = 0; e < 8; ++e) {
        float f = bf2f((u16)hv[e]);
        s += f; q += f * f;
      }
    }
    s += __shfl_xor(s, 1); q += __shfl_xor(q, 1);
    if (half == 0) {
      float mean = s * (1.f / 512.f);
      float var  = q * (1.f / 512.f) - mean * mean;
      muL[r] = mean;
      rsL[r] = rsqrtf(var + 1e-5f);
    }
  }
  f32x4 acc[4][4] = {};
  for (int kt = 0; kt < 8; ++kt) {
    int k0 = kt * 64;
    __syncthreads();
    #pragma unroll
    for (int t = 0; t < 4; ++t) {
      int ch = wave * 4 + t;
      GLDS16(att + (size_t)(m0 + ch * 8 + (lane >> 3)) * 512 + k0 + (lane & 7) * 8, &As[ch * 512]);
      GLDS16(BT + (size_t)(n0 + ch * 8 + (lane >> 3)) * 512 + k0 + (lane & 7) * 8, &Bs[ch * 512]);
    }
    __syncthreads();
    #pragma unroll
    for (int kk = 0; kk < 2; ++kk) {
      short8 af[4], bfr[4];
      #pragma unroll
      for (int m = 0; m < 4; ++m)
        af[m] = *(const short8*)&As[(wr * 64 + m * 16 + (lane & 15)) * 64 + kk * 32 + (lane >> 4) * 8];
      #pragma unroll
      for (int n = 0; n < 4; ++n)
        bfr[n] = *(const short8*)&Bs[(wc * 64 + n * 16 + (lane & 15)) * 64 + kk * 32 + (lane >> 4) * 8];
      #pragma unroll
      for (int m = 0; m < 4; ++m)
        #pragma unroll
        for (int n = 0; n < 4; ++n)
          MFMA_BF16(acc[m][n], af[m], bfr[n]);
    }
  }
  const int col0 = n0 + wc * 64;
  #pragma unroll
  for (int m = 0; m < 4; ++m) {
    int rl = wr * 64 + m * 16 + (lane >> 4) * 4;     // local row base (4-aligned)
    f32x4 muv = *(const f32x4*)&muL[rl];
    f32x4 rsv = *(const f32x4*)&rsL[rl];
    #pragma unroll
    for (int n = 0; n < 4; ++n) {
      int col = col0 + n * 16 + (lane & 15);
      float sg = Sg[col], cc = c2[col];
      #pragma unroll
      for (int i = 0; i < 4; ++i)
        out[(size_t)(m0 + rl + i) * 512 + col] = rsv[i] * (acc[m][n][i] - muv[i] * sg) + cc;
    }
  }
}

extern "C" void kernel_launch(void* const* d_in, const int* in_sizes, int n_in,
                              void* d_out, int out_size, void* d_ws, size_t ws_size,
                              hipStream_t stream) {
  const float* x    = (const float*)d_in[0];
  const float* Wqkv = (const float*)d_in[1];
  const float* ln_g = (const float*)d_in[2];
  const float* ln_b = (const float*)d_in[3];
  const float* Wo   = (const float*)d_in[4];
  const float* bo   = (const float*)d_in[5];
  float* out = (float*)d_out;
  char* ws = (char*)d_ws;

  u16*   xbf   = (u16*)(ws);                               // 16 MB  [16384][512]
  u16*   wqkvt = (u16*)(ws + 16777216);                    // 1.5 MB [1536][512]
  u16*   wgt   = (u16*)(ws + 18350080);                    // 0.5 MB [512][512] g-scaled
  u16*   qkb   = (u16*)(ws + 18874368);                    // 32 MB  [16384][1024]
  u16*   vtb   = (u16*)(ws + 52428800);                    // 16 MB  [b*512+d][1024]
  u16*   att   = (u16*)(ws + 69206016);                    // 16 MB  [16384][512] bf16
  float* Sg    = (float*)(ws + 85983232);                  // 2 KB
  float* c2    = (float*)(ws + 85985280);                  // 2 KB

  prep_kernel<<<4354, 256, 0, stream>>>(x, xbf, Wqkv, wqkvt, Wo, wgt,
                                        ln_g, ln_b, bo, Sg, c2);
  gemm_qkv_kernel<<<1536, 256, 0, stream>>>(xbf, wqkvt, qkb, vtb);
  attn_kernel<<<512, 256, 0, stream>>>(qkb, vtb, att);
  gemm_out_kernel<<<512, 256, 0, stream>>>(att, wgt, Sg, c2, out);
}

// Round 18
// 122.993 us; speedup vs baseline: 1.2682x; 1.2682x over previous
//
#include <hip/hip_runtime.h>
#include <cstdint>
#include <cstddef>

typedef unsigned short u16;
typedef float f32x4 __attribute__((ext_vector_type(4)));
typedef short short8 __attribute__((ext_vector_type(8)));
typedef u16 u16x4 __attribute__((ext_vector_type(4)));
typedef unsigned u32x2 __attribute__((ext_vector_type(2)));

// D = A*B + C  (16x16x32 bf16, fp32 acc).  A-frag: row=lane&15, k=(lane>>4)*8+e
// B-frag: col=lane&15, k=(lane>>4)*8+e.   C/D: col=lane&15, row=(lane>>4)*4+reg.
// The ONLY MFMA shape verified on this chip in this session; 16x16x16 NaNs,
// 32x32x16 produced finite-wrong output twice (rounds 7/8) — both banned.
// Round-11 lesson: no min-waves launch-bounds (64-VGPR cap => scratch spill).
// Round-17 lesson: a 2-block serial 512-iter reduction gates a 4354-block kernel
// at 55us (latency-bound, VALUBusy 2%) — parallelize small reductions.
#define MFMA_BF16(acc, a, b) \
  asm("v_mfma_f32_16x16x32_bf16 %0, %1, %2, %0" : "+v"(acc) : "v"(a), "v"(b))

// packed f32x2 -> bf16x2 (RNE; bit-identical to manual RNE — rounds 6/15 evidence)
#define CVT_PK(w, lo, hi) \
  asm("v_cvt_pk_bf16_f32 %0, %1, %2" : "=v"(w) : "v"(lo), "v"(hi))

// async global->LDS, 16B per lane; LDS dest = wave-uniform base + lane*16
#define GLDS16(gp, lp) __builtin_amdgcn_global_load_lds( \
    (__attribute__((address_space(1))) void*)(void*)(uintptr_t)(gp), \
    (__attribute__((address_space(3))) void*)(lp), 16, 0, 0)

static __device__ __forceinline__ u16 f2bf(float f) {
  union { float f; unsigned u; } x; x.f = f;
  unsigned u = x.u + 0x7fffu + ((x.u >> 16) & 1u);
  return (u16)(u >> 16);
}
static __device__ __forceinline__ float bf2f(u16 h) {
  union { unsigned u; float f; } x; x.u = (unsigned)h << 16; return x.f;
}

// ---------------- fused prep ----------------
// blocks [0,4096): x f32->bf16
// [4096,4288): Wqkv transpose (24x8), q-cols pre-scaled by 0.125
// [4288,4352): Wo transpose (8x8), rows pre-scaled by ln_g  ->  wgT[j][k]=g[k]Wo[k][j]
// [4352,4360): Sg[j] = sum_k bf16(g_k*Wo_kj);  c2[j] = sum_k b_k*Wo_kj + bo_j
//              8 blocks x 64 cols, 4-way k-split + LDS reduce (round-18 fix).
__global__ __launch_bounds__(256) void prep_kernel(const float* __restrict__ x,
                                                   u16* __restrict__ xbf,
                                                   const float* __restrict__ Wqkv,
                                                   u16* __restrict__ wqkvt,
                                                   const float* __restrict__ Wo,
                                                   u16* __restrict__ wgt,
                                                   const float* __restrict__ g,
                                                   const float* __restrict__ bvec,
                                                   const float* __restrict__ bo,
                                                   float* __restrict__ Sg,
                                                   float* __restrict__ c2) {
  __shared__ float tile[64][65];
  const int bid = blockIdx.x, tid = threadIdx.x;
  if (bid < 4096) {
    for (int i = bid * 256 + tid; i < 2097152; i += 4096 * 256) {
      f32x4 v = ((const f32x4*)x)[i];
      u16x4 o;
      o[0] = f2bf(v[0]); o[1] = f2bf(v[1]); o[2] = f2bf(v[2]); o[3] = f2bf(v[3]);
      ((u16x4*)xbf)[i] = o;
    }
    return;
  }
  if (bid < 4288) {                       // Wqkv transpose, 0.125 on q cols
    int t = bid - 4096; int bx = t % 24, by = t / 24;
    int c0 = bx * 64, r0 = by * 64;
    for (int t2 = tid; t2 < 4096; t2 += 256) {
      int r = t2 >> 6, c = t2 & 63;
      tile[r][c] = Wqkv[(size_t)(r0 + r) * 1536 + c0 + c];
    }
    __syncthreads();
    for (int t2 = tid; t2 < 4096; t2 += 256) {
      int rr = t2 >> 6, cc = t2 & 63;
      float sc = (c0 + rr) < 512 ? 0.125f : 1.0f;
      wqkvt[(size_t)(c0 + rr) * 512 + r0 + cc] = f2bf(tile[cc][rr] * sc);
    }
    return;
  }
  if (bid < 4352) {                       // Wo transpose with g row-scale
    int t = bid - 4288; int bx = t & 7, by = t >> 3;
    int c0 = bx * 64, r0 = by * 64;
    for (int t2 = tid; t2 < 4096; t2 += 256) {
      int r = t2 >> 6, c = t2 & 63;
      tile[r][c] = Wo[(size_t)(r0 + r) * 512 + c0 + c];
    }
    __syncthreads();
    for (int t2 = tid; t2 < 4096; t2 += 256) {
      int rr = t2 >> 6, cc = t2 & 63;
      wgt[(size_t)(c0 + rr) * 512 + r0 + cc] = f2bf(tile[cc][rr] * g[r0 + cc]);
    }
    return;
  }
  {                                       // Sg / c2: 8 blocks x 64 cols, k parallelized
    float* sgL = &tile[0][0];             // [4][64]
    float* ccL = &tile[0][0] + 256;       // [4][64]
    const int bb = bid - 4352;
    const int jc = tid & 63, kp = tid >> 6;
    const int j = bb * 64 + jc;
    float sg = 0.f, cc = 0.f;
    #pragma unroll 4
    for (int k = kp * 128; k < (kp + 1) * 128; ++k) {
      float w = Wo[(size_t)k * 512 + j];
      sg += bf2f(f2bf(g[k] * w));         // match MFMA's bf16 quantization of Wg
      cc += bvec[k] * w;
    }
    sgL[kp * 64 + jc] = sg;
    ccL[kp * 64 + jc] = cc;
    __syncthreads();
    if (kp == 0) {
      float s = sgL[jc] + sgL[64 + jc] + sgL[128 + jc] + sgL[192 + jc];
      float c = ccL[jc] + ccL[64 + jc] + ccL[128 + jc] + ccL[192 + jc];
      Sg[j] = s;
      c2[j] = c + bo[j];
    }
  }
}

// ---------------- GEMM1: qkv = x_bf16[16384,512] @ WqkvT[1536,512]^T ----------------
// cols 0..1023 -> qk buffer [16384][1024] (q pre-scaled by 0.125 via Wqkv);
// cols 1024..1535 (v) -> vT[b*512+d][1024] via LDS transpose (coalesced writes).
// Grid: 1D 1536, XCD-chunked decode.  Packed cvt_pk epilogues.
__global__ __launch_bounds__(256) void gemm_qkv_kernel(const u16* __restrict__ A,
                                                       const u16* __restrict__ BT,
                                                       u16* __restrict__ qk,
                                                       u16* __restrict__ vT) {
  __shared__ u16 smem[16896];          // 33792 B; As=smem[0:8192], Bs=smem[8192:16384]
  u16* As = smem;
  u16* Bs = smem + 8192;
  const int tid = threadIdx.x, lane = tid & 63, wave = tid >> 6;
  const int wr = wave >> 1, wc = wave & 1;
  const int bid = blockIdx.x;
  const int lin = (bid & 7) * 192 + (bid >> 3);        // bijective: 1536 % 8 == 0
  const int my = lin / 12, nx = lin - my * 12;
  const int m0 = my * 128, n0 = nx * 128;
  f32x4 acc[4][4] = {};
  for (int kt = 0; kt < 8; ++kt) {
    int k0 = kt * 64;
    __syncthreads();
    #pragma unroll
    for (int t = 0; t < 4; ++t) {
      int ch = wave * 4 + t;
      GLDS16(A + (size_t)(m0 + ch * 8 + (lane >> 3)) * 512 + k0 + (lane & 7) * 8, &As[ch * 512]);
      GLDS16(BT + (size_t)(n0 + ch * 8 + (lane >> 3)) * 512 + k0 + (lane & 7) * 8, &Bs[ch * 512]);
    }
    __syncthreads();
    #pragma unroll
    for (int kk = 0; kk < 2; ++kk) {
      short8 af[4], bfr[4];
      #pragma unroll
      for (int m = 0; m < 4; ++m)
        af[m] = *(const short8*)&As[(wr * 64 + m * 16 + (lane & 15)) * 64 + kk * 32 + (lane >> 4) * 8];
      #pragma unroll
      for (int n = 0; n < 4; ++n)
        bfr[n] = *(const short8*)&Bs[(wc * 64 + n * 16 + (lane & 15)) * 64 + kk * 32 + (lane >> 4) * 8];
      #pragma unroll
      for (int m = 0; m < 4; ++m)
        #pragma unroll
        for (int n = 0; n < 4; ++n)
          MFMA_BF16(acc[m][n], af[m], bfr[n]);
    }
  }
  const int row0 = m0 + wr * 64, col0 = n0 + wc * 64;
  if (n0 < 1024) {
    #pragma unroll
    for (int m = 0; m < 4; ++m) {
      int row = row0 + m * 16 + (lane >> 4) * 4;
      #pragma unroll
      for (int n = 0; n < 4; ++n) {
        int col = col0 + n * 16 + (lane & 15);
        unsigned w0, w1;
        CVT_PK(w0, acc[m][n][0], acc[m][n][1]);
        CVT_PK(w1, acc[m][n][2], acc[m][n][3]);
        qk[(size_t)(row + 0) * 1024 + col] = (u16)(w0 & 0xffffu);
        qk[(size_t)(row + 1) * 1024 + col] = (u16)(w0 >> 16);
        qk[(size_t)(row + 2) * 1024 + col] = (u16)(w1 & 0xffffu);
        qk[(size_t)(row + 3) * 1024 + col] = (u16)(w1 >> 16);
      }
    }
  } else {
    // V block: transpose through LDS, then coalesced global writes.
    __syncthreads();                   // all As/Bs reads done; smem reused as Td[128][132]
    const int lo = lane & 15, g = lane >> 4;
    #pragma unroll
    for (int m = 0; m < 4; ++m) {
      int tl0 = wr * 64 + m * 16 + g * 4;          // token_local base (4 consecutive)
      #pragma unroll
      for (int n = 0; n < 4; ++n) {
        int dl = wc * 64 + n * 16 + lo;            // d_local
        u32x2 pk2;
        CVT_PK(pk2[0], acc[m][n][0], acc[m][n][1]);
        CVT_PK(pk2[1], acc[m][n][2], acc[m][n][3]);
        *(u32x2*)&smem[dl * 132 + tl0] = pk2;      // Td[dl][tl0..tl0+3]
      }
    }
    __syncthreads();
    const int bb = m0 >> 10, nn0 = m0 & 1023, d0 = n0 - 1024;
    for (int t = tid; t < 128 * 32; t += 256) {    // 128 d-rows x 32 8B-segs
      int d = t >> 5, sg = t & 31;
      u16x4 v = *(const u16x4*)&smem[d * 132 + sg * 4];
      *(u16x4*)&vT[(size_t)(bb * 512 + d0 + d) * 1024 + nn0 + sg * 4] = v;
    }
  }
}

// ---------------- attention: O = relu(Q K^T) @ V  (scale pre-folded into Q) ----------------
// 2 q-tiles per block (round-14-verified), packed cvt_pk conversions (round-15).
__global__ __launch_bounds__(256) void attn_kernel(const u16* __restrict__ qk,
                                                   const u16* __restrict__ vT,
                                                   u16* __restrict__ aout) {
  __shared__ u16 smem[32768];          // 65536 B
  u16* Ks = smem;                      // [128][64]  bytes 0..16K
  u16* Vs = smem + 8192;               // [64][128]  bytes 16K..32K
  u16* Ss = smem + 16384;              // [128][128] bytes 32K..64K (no aliasing)
  const int tid = threadIdx.x, lane = tid & 63, wave = tid >> 6;
  const int wr = wave >> 1, wc = wave & 1;
  const int L = blockIdx.x;
  const int qt2 = L >> 7, bh = L & 127, h = bh & 7, b = bh >> 3;
  const size_t qrow0 = (size_t)b * 1024 + qt2 * 256;

  short8 qf[2][4][2];
  #pragma unroll
  for (int q = 0; q < 2; ++q)
    #pragma unroll
    for (int m = 0; m < 4; ++m)
      #pragma unroll
      for (int kk = 0; kk < 2; ++kk)
        qf[q][m][kk] = *(const short8*)&qk[(qrow0 + q * 128 + wr * 64 + m * 16 + (lane & 15)) * 1024
                                           + h * 64 + kk * 32 + (lane >> 4) * 8];
  f32x4 acc[2][4][2] = {};
  for (int jt = 0; jt < 8; ++jt) {
    __syncthreads();                                         // prev jt Ks/Vs/Ss reads done
    const u16* Kg = qk + ((size_t)b * 1024 + jt * 128) * 1024 + 512 + h * 64;
    const u16* Vg = vT + ((size_t)b * 512 + h * 64) * 1024 + jt * 128;
    #pragma unroll
    for (int t = 0; t < 4; ++t) {
      int ch = wave * 4 + t;
      GLDS16(Kg + (size_t)(ch * 8 + (lane >> 3)) * 1024 + ((lane & 7) ^ (lane >> 3)) * 8,
             &Ks[ch * 512]);
      GLDS16(Vg + (size_t)(ch * 4 + (lane >> 4)) * 1024 + ((lane & 15) ^ (t * 4 + (lane >> 4))) * 8,
             &Vs[ch * 512]);
    }
    __syncthreads();                                         // K,V staged
    #pragma unroll
    for (int q = 0; q < 2; ++q) {
      // S^T = K.Q^T : sacc[n][m] tile has row=j_local, col=i_local
      f32x4 sacc[4][4] = {};
      __builtin_amdgcn_s_setprio(1);
      #pragma unroll
      for (int kk = 0; kk < 2; ++kk) {
        short8 kf[4];
        #pragma unroll
        for (int n = 0; n < 4; ++n) {
          int r = wc * 64 + n * 16 + (lane & 15);
          int slot = kk * 4 + (lane >> 4);                   // 0..7
          kf[n] = *(const short8*)&Ks[r * 64 + ((slot ^ (r & 7)) * 8)];
        }
        #pragma unroll
        for (int n = 0; n < 4; ++n)
          #pragma unroll
          for (int m = 0; m < 4; ++m)
            MFMA_BF16(sacc[n][m], kf[n], qf[q][m][kk]);
      }
      __builtin_amdgcn_s_setprio(0);
      if (q == 1) __syncthreads();                           // PV(q0) Ss reads done
      // S-write (q==0 needs no pre-barrier: prev Ss readers fenced at loop top)
      #pragma unroll
      for (int m = 0; m < 4; ++m) {
        int i = wr * 64 + m * 16 + (lane & 15);
        unsigned rowbase = (unsigned)i * 256;                // byte offset of S row
        unsigned sw = (unsigned)(i & 15) << 4;
        #pragma unroll
        for (int n = 0; n < 4; ++n) {
          int j0 = wc * 64 + n * 16 + (lane >> 4) * 4;
          float a0 = fmaxf(sacc[n][m][0], 0.f), a1 = fmaxf(sacc[n][m][1], 0.f);
          float a2 = fmaxf(sacc[n][m][2], 0.f), a3 = fmaxf(sacc[n][m][3], 0.f);
          u32x2 pk2;
          CVT_PK(pk2[0], a0, a1);
          CVT_PK(pk2[1], a2, a3);
          *(u32x2*)((char*)Ss + (rowbase + (((unsigned)j0 * 2) ^ sw))) = pk2;
        }
      }
      __syncthreads();                                       // S visible
      __builtin_amdgcn_s_setprio(1);
      #pragma unroll
      for (int ks = 0; ks < 4; ++ks) {
        short8 sa[4], vb[2];
        #pragma unroll
        for (int m = 0; m < 4; ++m) {
          int i = wr * 64 + m * 16 + (lane & 15);
          unsigned c2v = (unsigned)(ks * 32 + (lane >> 4) * 8) * 2;
          sa[m] = *(const short8*)((const char*)Ss + (unsigned)i * 256 + (c2v ^ ((unsigned)(i & 15) << 4)));
        }
        #pragma unroll
        for (int n = 0; n < 2; ++n) {
          int r = wc * 32 + n * 16 + (lane & 15);
          int slot = ks * 4 + (lane >> 4);                   // 0..15
          vb[n] = *(const short8*)&Vs[r * 128 + ((slot ^ (r & 15)) * 8)];
        }
        #pragma unroll
        for (int m = 0; m < 4; ++m)
          #pragma unroll
          for (int n = 0; n < 2; ++n)
            MFMA_BF16(acc[q][m][n], sa[m], vb[n]);
      }
      __builtin_amdgcn_s_setprio(0);
    }
  }
  #pragma unroll
  for (int q = 0; q < 2; ++q)
    #pragma unroll
    for (int m = 0; m < 4; ++m) {
      int row = q * 128 + wr * 64 + m * 16 + (lane >> 4) * 4;
      #pragma unroll
      for (int n = 0; n < 2; ++n) {
        int col = h * 64 + wc * 32 + n * 16 + (lane & 15);
        unsigned w0, w1;
        CVT_PK(w0, acc[q][m][n][0], acc[q][m][n][1]);
        CVT_PK(w1, acc[q][m][n][2], acc[q][m][n][3]);
        aout[(qrow0 + row + 0) * 512 + col] = (u16)(w0 & 0xffffu);
        aout[(qrow0 + row + 1) * 512 + col] = (u16)(w0 >> 16);
        aout[(qrow0 + row + 2) * 512 + col] = (u16)(w1 & 0xffffu);
        aout[(qrow0 + row + 3) * 512 + col] = (u16)(w1 >> 16);
      }
    }
}

// ---------------- GEMM2 + fused LayerNorm ----------------
// out[i,j] = rstd_i*(rawdot[i,j] - mu_i*Sg[j]) + c2[j],  rawdot = att @ wgT^T
// (LN commuted through the GEMM; g folded into wgT, b/bo folded into c2.)
// Stats prologue: 2 threads/row over att rows m0..m0+127 -> mu/rstd in LDS.
// Grid: 1D 512, XCD-chunked decode.
__global__ __launch_bounds__(256) void gemm_out_kernel(const u16* __restrict__ att,
                                                       const u16* __restrict__ BT,
                                                       const float* __restrict__ Sg,
                                                       const float* __restrict__ c2,
                                                       float* __restrict__ out) {
  __shared__ u16 smem[16896];          // As 16KB | Bs 16KB | muL 512B | rsL 512B
  u16* As = smem;
  u16* Bs = smem + 8192;
  float* muL = (float*)&smem[16384];   // [128]
  float* rsL = (float*)&smem[16640];   // [128]
  const int tid = threadIdx.x, lane = tid & 63, wave = tid >> 6;
  const int wr = wave >> 1, wc = wave & 1;
  const int bid = blockIdx.x;
  const int lin = (bid & 7) * 64 + (bid >> 3);
  const int m0 = (lin >> 2) * 128, n0 = (lin & 3) * 128;
  // ---- LN stats for this block's 128 rows ----
  {
    const int r = tid >> 1, half = tid & 1;
    const u16* ar = att + (size_t)(m0 + r) * 512 + half * 256;
    float s = 0.f, q = 0.f;
    #pragma unroll
    for (int i = 0; i < 32; ++i) {
      short8 hv = *(const short8*)&ar[i * 8];
      #pragma unroll
      for (int e = 0; e < 8; ++e) {
        float f = bf2f((u16)hv[e]);
        s += f; q += f * f;
      }
    }
    s += __shfl_xor(s, 1); q += __shfl_xor(q, 1);
    if (half == 0) {
      float mean = s * (1.f / 512.f);
      float var  = q * (1.f / 512.f) - mean * mean;
      muL[r] = mean;
      rsL[r] = rsqrtf(var + 1e-5f);
    }
  }
  f32x4 acc[4][4] = {};
  for (int kt = 0; kt < 8; ++kt) {
    int k0 = kt * 64;
    __syncthreads();
    #pragma unroll
    for (int t = 0; t < 4; ++t) {
      int ch = wave * 4 + t;
      GLDS16(att + (size_t)(m0 + ch * 8 + (lane >> 3)) * 512 + k0 + (lane & 7) * 8, &As[ch * 512]);
      GLDS16(BT + (size_t)(n0 + ch * 8 + (lane >> 3)) * 512 + k0 + (lane & 7) * 8, &Bs[ch * 512]);
    }
    __syncthreads();
    #pragma unroll
    for (int kk = 0; kk < 2; ++kk) {
      short8 af[4], bfr[4];
      #pragma unroll
      for (int m = 0; m < 4; ++m)
        af[m] = *(const short8*)&As[(wr * 64 + m * 16 + (lane & 15)) * 64 + kk * 32 + (lane >> 4) * 8];
      #pragma unroll
      for (int n = 0; n < 4; ++n)
        bfr[n] = *(const short8*)&Bs[(wc * 64 + n * 16 + (lane & 15)) * 64 + kk * 32 + (lane >> 4) * 8];
      #pragma unroll
      for (int m = 0; m < 4; ++m)
        #pragma unroll
        for (int n = 0; n < 4; ++n)
          MFMA_BF16(acc[m][n], af[m], bfr[n]);
    }
  }
  const int col0 = n0 + wc * 64;
  #pragma unroll
  for (int m = 0; m < 4; ++m) {
    int rl = wr * 64 + m * 16 + (lane >> 4) * 4;     // local row base (4-aligned)
    f32x4 muv = *(const f32x4*)&muL[rl];
    f32x4 rsv = *(const f32x4*)&rsL[rl];
    #pragma unroll
    for (int n = 0; n < 4; ++n) {
      int col = col0 + n * 16 + (lane & 15);
      float sg = Sg[col], cc = c2[col];
      #pragma unroll
      for (int i = 0; i < 4; ++i)
        out[(size_t)(m0 + rl + i) * 512 + col] = rsv[i] * (acc[m][n][i] - muv[i] * sg) + cc;
    }
  }
}

extern "C" void kernel_launch(void* const* d_in, const int* in_sizes, int n_in,
                              void* d_out, int out_size, void* d_ws, size_t ws_size,
                              hipStream_t stream) {
  const float* x    = (const float*)d_in[0];
  const float* Wqkv = (const float*)d_in[1];
  const float* ln_g = (const float*)d_in[2];
  const float* ln_b = (const float*)d_in[3];
  const float* Wo   = (const float*)d_in[4];
  const float* bo   = (const float*)d_in[5];
  float* out = (float*)d_out;
  char* ws = (char*)d_ws;

  u16*   xbf   = (u16*)(ws);                               // 16 MB  [16384][512]
  u16*   wqkvt = (u16*)(ws + 16777216);                    // 1.5 MB [1536][512]
  u16*   wgt   = (u16*)(ws + 18350080);                    // 0.5 MB [512][512] g-scaled
  u16*   qkb   = (u16*)(ws + 18874368);                    // 32 MB  [16384][1024]
  u16*   vtb   = (u16*)(ws + 52428800);                    // 16 MB  [b*512+d][1024]
  u16*   att   = (u16*)(ws + 69206016);                    // 16 MB  [16384][512] bf16
  float* Sg    = (float*)(ws + 85983232);                  // 2 KB
  float* c2    = (float*)(ws + 85985280);                  // 2 KB

  prep_kernel<<<4360, 256, 0, stream>>>(x, xbf, Wqkv, wqkvt, Wo, wgt,
                                        ln_g, ln_b, bo, Sg, c2);
  gemm_qkv_kernel<<<1536, 256, 0, stream>>>(xbf, wqkvt, qkb, vtb);
  attn_kernel<<<512, 256, 0, stream>>>(qkb, vtb, att);
  gemm_out_kernel<<<512, 256, 0, stream>>>(att, wgt, Sg, c2, out);
}

// Round 19
// 116.007 us; speedup vs baseline: 1.3445x; 1.0602x over previous
//
#include <hip/hip_runtime.h>
#include <cstdint>
#include <cstddef>

typedef unsigned short u16;
typedef float f32x4 __attribute__((ext_vector_type(4)));
typedef short short8 __attribute__((ext_vector_type(8)));
typedef u16 u16x4 __attribute__((ext_vector_type(4)));
typedef unsigned u32x2 __attribute__((ext_vector_type(2)));

// D = A*B + C  (16x16x32 bf16, fp32 acc).  A-frag: row=lane&15, k=(lane>>4)*8+e
// B-frag: col=lane&15, k=(lane>>4)*8+e.   C/D: col=lane&15, row=(lane>>4)*4+reg.
// The ONLY MFMA shape verified on this chip in this session; 16x16x16 NaNs,
// 32x32x16 produced finite-wrong output twice (rounds 7/8) — both banned.
// Round-11 lesson: no min-waves launch-bounds (64-VGPR cap => scratch spill).
// Round-17/18 lesson: LN-into-GEMM fusion is net-negative (stats prologue re-reads
// the A panel per block, 64MB extra + latency-exposed); keep the dedicated ln kernel.
#define MFMA_BF16(acc, a, b) \
  asm("v_mfma_f32_16x16x32_bf16 %0, %1, %2, %0" : "+v"(acc) : "v"(a), "v"(b))

// packed f32x2 -> bf16x2 (RNE; bit-identical to manual RNE — rounds 6/15 evidence)
#define CVT_PK(w, lo, hi) \
  asm("v_cvt_pk_bf16_f32 %0, %1, %2" : "=v"(w) : "v"(lo), "v"(hi))

// async global->LDS, 16B per lane; LDS dest = wave-uniform base + lane*16
#define GLDS16(gp, lp) __builtin_amdgcn_global_load_lds( \
    (__attribute__((address_space(1))) void*)(void*)(uintptr_t)(gp), \
    (__attribute__((address_space(3))) void*)(lp), 16, 0, 0)

static __device__ __forceinline__ u16 f2bf(float f) {
  union { float f; unsigned u; } x; x.f = f;
  unsigned u = x.u + 0x7fffu + ((x.u >> 16) & 1u);
  return (u16)(u >> 16);
}

// ---------------- fused prep: cvt(x) | tcvt(Wqkv, scaled) | tcvt(Wo) ----------------
// blocks [0,4096): x f32->bf16; [4096,4288): Wqkv transpose (24x8); [4288,4352): Wo (8x8).
__global__ __launch_bounds__(256) void prep_kernel(const float* __restrict__ x,
                                                   u16* __restrict__ xbf,
                                                   const float* __restrict__ Wqkv,
                                                   u16* __restrict__ wqkvt,
                                                   const float* __restrict__ Wo,
                                                   u16* __restrict__ wot) {
  __shared__ float tile[64][65];
  const int bid = blockIdx.x, tid = threadIdx.x;
  if (bid < 4096) {
    for (int i = bid * 256 + tid; i < 2097152; i += 4096 * 256) {
      f32x4 v = ((const f32x4*)x)[i];
      u16x4 o;
      o[0] = f2bf(v[0]); o[1] = f2bf(v[1]); o[2] = f2bf(v[2]); o[3] = f2bf(v[3]);
      ((u16x4*)xbf)[i] = o;
    }
    return;
  }
  const float* src; u16* dst; int R, C, sclim, bx, by;
  if (bid < 4288) {
    int t = bid - 4096; bx = t % 24; by = t / 24;
    src = Wqkv; dst = wqkvt; R = 512; C = 1536; sclim = 512;
  } else {
    int t = bid - 4288; bx = t & 7; by = t >> 3;
    src = Wo; dst = wot; R = 512; C = 512; sclim = 0;
  }
  int c0 = bx * 64, r0 = by * 64;
  for (int t = tid; t < 4096; t += 256) {
    int r = t >> 6, c = t & 63;
    tile[r][c] = src[(size_t)(r0 + r) * C + c0 + c];
  }
  __syncthreads();
  for (int t = tid; t < 4096; t += 256) {
    int rr = t >> 6, cc = t & 63;
    float sc = (c0 + rr) < sclim ? 0.125f : 1.0f;
    dst[(size_t)(c0 + rr) * R + r0 + cc] = f2bf(tile[cc][rr] * sc);
  }
}

// ---------------- GEMM1: qkv = x_bf16[16384,512] @ WqkvT[1536,512]^T ----------------
// cols 0..1023 -> qk buffer [16384][1024] (q pre-scaled by 0.125 via Wqkv);
// cols 1024..1535 (v) -> vT[b*512+d][1024] via LDS transpose (coalesced writes).
// Grid: 1D 1536, XCD-chunked decode.  Packed cvt_pk epilogues.
__global__ __launch_bounds__(256) void gemm_qkv_kernel(const u16* __restrict__ A,
                                                       const u16* __restrict__ BT,
                                                       u16* __restrict__ qk,
                                                       u16* __restrict__ vT) {
  __shared__ u16 smem[16896];          // 33792 B; As=smem[0:8192], Bs=smem[8192:16384]
  u16* As = smem;
  u16* Bs = smem + 8192;
  const int tid = threadIdx.x, lane = tid & 63, wave = tid >> 6;
  const int wr = wave >> 1, wc = wave & 1;
  const int bid = blockIdx.x;
  const int lin = (bid & 7) * 192 + (bid >> 3);        // bijective: 1536 % 8 == 0
  const int my = lin / 12, nx = lin - my * 12;
  const int m0 = my * 128, n0 = nx * 128;
  f32x4 acc[4][4] = {};
  for (int kt = 0; kt < 8; ++kt) {
    int k0 = kt * 64;
    __syncthreads();
    #pragma unroll
    for (int t = 0; t < 4; ++t) {
      int ch = wave * 4 + t;
      GLDS16(A + (size_t)(m0 + ch * 8 + (lane >> 3)) * 512 + k0 + (lane & 7) * 8, &As[ch * 512]);
      GLDS16(BT + (size_t)(n0 + ch * 8 + (lane >> 3)) * 512 + k0 + (lane & 7) * 8, &Bs[ch * 512]);
    }
    __syncthreads();
    #pragma unroll
    for (int kk = 0; kk < 2; ++kk) {
      short8 af[4], bfr[4];
      #pragma unroll
      for (int m = 0; m < 4; ++m)
        af[m] = *(const short8*)&As[(wr * 64 + m * 16 + (lane & 15)) * 64 + kk * 32 + (lane >> 4) * 8];
      #pragma unroll
      for (int n = 0; n < 4; ++n)
        bfr[n] = *(const short8*)&Bs[(wc * 64 + n * 16 + (lane & 15)) * 64 + kk * 32 + (lane >> 4) * 8];
      #pragma unroll
      for (int m = 0; m < 4; ++m)
        #pragma unroll
        for (int n = 0; n < 4; ++n)
          MFMA_BF16(acc[m][n], af[m], bfr[n]);
    }
  }
  const int row0 = m0 + wr * 64, col0 = n0 + wc * 64;
  if (n0 < 1024) {
    #pragma unroll
    for (int m = 0; m < 4; ++m) {
      int row = row0 + m * 16 + (lane >> 4) * 4;
      #pragma unroll
      for (int n = 0; n < 4; ++n) {
        int col = col0 + n * 16 + (lane & 15);
        unsigned w0, w1;
        CVT_PK(w0, acc[m][n][0], acc[m][n][1]);
        CVT_PK(w1, acc[m][n][2], acc[m][n][3]);
        qk[(size_t)(row + 0) * 1024 + col] = (u16)(w0 & 0xffffu);
        qk[(size_t)(row + 1) * 1024 + col] = (u16)(w0 >> 16);
        qk[(size_t)(row + 2) * 1024 + col] = (u16)(w1 & 0xffffu);
        qk[(size_t)(row + 3) * 1024 + col] = (u16)(w1 >> 16);
      }
    }
  } else {
    // V block: transpose through LDS, then coalesced global writes.
    __syncthreads();                   // all As/Bs reads done; smem reused as Td[128][132]
    const int lo = lane & 15, g = lane >> 4;
    #pragma unroll
    for (int m = 0; m < 4; ++m) {
      int tl0 = wr * 64 + m * 16 + g * 4;          // token_local base (4 consecutive)
      #pragma unroll
      for (int n = 0; n < 4; ++n) {
        int dl = wc * 64 + n * 16 + lo;            // d_local
        u32x2 pk2;
        CVT_PK(pk2[0], acc[m][n][0], acc[m][n][1]);
        CVT_PK(pk2[1], acc[m][n][2], acc[m][n][3]);
        *(u32x2*)&smem[dl * 132 + tl0] = pk2;      // Td[dl][tl0..tl0+3]
      }
    }
    __syncthreads();
    const int bb = m0 >> 10, nn0 = m0 & 1023, d0 = n0 - 1024;
    for (int t = tid; t < 128 * 32; t += 256) {    // 128 d-rows x 32 8B-segs
      int d = t >> 5, sg = t & 31;
      u16x4 v = *(const u16x4*)&smem[d * 132 + sg * 4];
      *(u16x4*)&vT[(size_t)(bb * 512 + d0 + d) * 1024 + nn0 + sg * 4] = v;
    }
  }
}

// ---------------- attention: O = relu(Q K^T) @ V  (scale pre-folded into Q) ----------------
// 2 q-tiles per block (round-14-verified), packed cvt_pk conversions (round-15).
__global__ __launch_bounds__(256) void attn_kernel(const u16* __restrict__ qk,
                                                   const u16* __restrict__ vT,
                                                   u16* __restrict__ aout) {
  __shared__ u16 smem[32768];          // 65536 B
  u16* Ks = smem;                      // [128][64]  bytes 0..16K
  u16* Vs = smem + 8192;               // [64][128]  bytes 16K..32K
  u16* Ss = smem + 16384;              // [128][128] bytes 32K..64K (no aliasing)
  const int tid = threadIdx.x, lane = tid & 63, wave = tid >> 6;
  const int wr = wave >> 1, wc = wave & 1;
  const int L = blockIdx.x;
  const int qt2 = L >> 7, bh = L & 127, h = bh & 7, b = bh >> 3;
  const size_t qrow0 = (size_t)b * 1024 + qt2 * 256;

  short8 qf[2][4][2];
  #pragma unroll
  for (int q = 0; q < 2; ++q)
    #pragma unroll
    for (int m = 0; m < 4; ++m)
      #pragma unroll
      for (int kk = 0; kk < 2; ++kk)
        qf[q][m][kk] = *(const short8*)&qk[(qrow0 + q * 128 + wr * 64 + m * 16 + (lane & 15)) * 1024
                                           + h * 64 + kk * 32 + (lane >> 4) * 8];
  f32x4 acc[2][4][2] = {};
  for (int jt = 0; jt < 8; ++jt) {
    __syncthreads();                                         // prev jt Ks/Vs/Ss reads done
    const u16* Kg = qk + ((size_t)b * 1024 + jt * 128) * 1024 + 512 + h * 64;
    const u16* Vg = vT + ((size_t)b * 512 + h * 64) * 1024 + jt * 128;
    #pragma unroll
    for (int t = 0; t < 4; ++t) {
      int ch = wave * 4 + t;
      GLDS16(Kg + (size_t)(ch * 8 + (lane >> 3)) * 1024 + ((lane & 7) ^ (lane >> 3)) * 8,
             &Ks[ch * 512]);
      GLDS16(Vg + (size_t)(ch * 4 + (lane >> 4)) * 1024 + ((lane & 15) ^ (t * 4 + (lane >> 4))) * 8,
             &Vs[ch * 512]);
    }
    __syncthreads();                                         // K,V staged
    #pragma unroll
    for (int q = 0; q < 2; ++q) {
      // S^T = K.Q^T : sacc[n][m] tile has row=j_local, col=i_local
      f32x4 sacc[4][4] = {};
      __builtin_amdgcn_s_setprio(1);
      #pragma unroll
      for (int kk = 0; kk < 2; ++kk) {
        short8 kf[4];
        #pragma unroll
        for (int n = 0; n < 4; ++n) {
          int r = wc * 64 + n * 16 + (lane & 15);
          int slot = kk * 4 + (lane >> 4);                   // 0..7
          kf[n] = *(const short8*)&Ks[r * 64 + ((slot ^ (r & 7)) * 8)];
        }
        #pragma unroll
        for (int n = 0; n < 4; ++n)
          #pragma unroll
          for (int m = 0; m < 4; ++m)
            MFMA_BF16(sacc[n][m], kf[n], qf[q][m][kk]);
      }
      __builtin_amdgcn_s_setprio(0);
      if (q == 1) __syncthreads();                           // PV(q0) Ss reads done
      // S-write (q==0 needs no pre-barrier: prev Ss readers fenced at loop top)
      #pragma unroll
      for (int m = 0; m < 4; ++m) {
        int i = wr * 64 + m * 16 + (lane & 15);
        unsigned rowbase = (unsigned)i * 256;                // byte offset of S row
        unsigned sw = (unsigned)(i & 15) << 4;
        #pragma unroll
        for (int n = 0; n < 4; ++n) {
          int j0 = wc * 64 + n * 16 + (lane >> 4) * 4;
          float a0 = fmaxf(sacc[n][m][0], 0.f), a1 = fmaxf(sacc[n][m][1], 0.f);
          float a2 = fmaxf(sacc[n][m][2], 0.f), a3 = fmaxf(sacc[n][m][3], 0.f);
          u32x2 pk2;
          CVT_PK(pk2[0], a0, a1);
          CVT_PK(pk2[1], a2, a3);
          *(u32x2*)((char*)Ss + (rowbase + (((unsigned)j0 * 2) ^ sw))) = pk2;
        }
      }
      __syncthreads();                                       // S visible
      __builtin_amdgcn_s_setprio(1);
      #pragma unroll
      for (int ks = 0; ks < 4; ++ks) {
        short8 sa[4], vb[2];
        #pragma unroll
        for (int m = 0; m < 4; ++m) {
          int i = wr * 64 + m * 16 + (lane & 15);
          unsigned c2v = (unsigned)(ks * 32 + (lane >> 4) * 8) * 2;
          sa[m] = *(const short8*)((const char*)Ss + (unsigned)i * 256 + (c2v ^ ((unsigned)(i & 15) << 4)));
        }
        #pragma unroll
        for (int n = 0; n < 2; ++n) {
          int r = wc * 32 + n * 16 + (lane & 15);
          int slot = ks * 4 + (lane >> 4);                   // 0..15
          vb[n] = *(const short8*)&Vs[r * 128 + ((slot ^ (r & 15)) * 8)];
        }
        #pragma unroll
        for (int m = 0; m < 4; ++m)
          #pragma unroll
          for (int n = 0; n < 2; ++n)
            MFMA_BF16(acc[q][m][n], sa[m], vb[n]);
      }
      __builtin_amdgcn_s_setprio(0);
    }
  }
  #pragma unroll
  for (int q = 0; q < 2; ++q)
    #pragma unroll
    for (int m = 0; m < 4; ++m) {
      int row = q * 128 + wr * 64 + m * 16 + (lane >> 4) * 4;
      #pragma unroll
      for (int n = 0; n < 2; ++n) {
        int col = h * 64 + wc * 32 + n * 16 + (lane & 15);
        unsigned w0, w1;
        CVT_PK(w0, acc[q][m][n][0], acc[q][m][n][1]);
        CVT_PK(w1, acc[q][m][n][2], acc[q][m][n][3]);
        aout[(qrow0 + row + 0) * 512 + col] = (u16)(w0 & 0xffffu);
        aout[(qrow0 + row + 1) * 512 + col] = (u16)(w0 >> 16);
        aout[(qrow0 + row + 2) * 512 + col] = (u16)(w1 & 0xffffu);
        aout[(qrow0 + row + 3) * 512 + col] = (u16)(w1 >> 16);
      }
    }
}

// ---------------- LayerNorm over 512, one wave per row, bf16 in -> bf16 out ----------------
__global__ __launch_bounds__(256) void ln_kernel(const u16* __restrict__ x,
                                                 const float* __restrict__ g,
                                                 const float* __restrict__ bt,
                                                 u16* __restrict__ y) {
  const int lane = threadIdx.x & 63, wave = threadIdx.x >> 6;
  const size_t row = (size_t)blockIdx.x * 4 + wave;
  const u16* xr = x + row * 512;
  u16x4 h0 = *(const u16x4*)&xr[lane * 8];
  u16x4 h1 = *(const u16x4*)&xr[lane * 8 + 4];
  float v[8];
  #pragma unroll
  for (int i = 0; i < 4; ++i) {
    union { unsigned u; float f; } a, bu;
    a.u = (unsigned)h0[i] << 16;  v[i] = a.f;
    bu.u = (unsigned)h1[i] << 16; v[4 + i] = bu.f;
  }
  float s = 0.f, q = 0.f;
  #pragma unroll
  for (int i = 0; i < 8; ++i) { s += v[i]; q += v[i] * v[i]; }
  #pragma unroll
  for (int o = 32; o > 0; o >>= 1) { s += __shfl_xor(s, o); q += __shfl_xor(q, o); }
  float mean = s * (1.f / 512.f);
  float var  = q * (1.f / 512.f) - mean * mean;
  float rstd = rsqrtf(var + 1e-5f);
  f32x4 g0 = *(const f32x4*)&g[lane * 8],  g1 = *(const f32x4*)&g[lane * 8 + 4];
  f32x4 b0 = *(const f32x4*)&bt[lane * 8], b1 = *(const f32x4*)&bt[lane * 8 + 4];
  u16x4 o0, o1;
  #pragma unroll
  for (int i = 0; i < 4; ++i) {
    o0[i] = f2bf((v[i] - mean) * rstd * g0[i] + b0[i]);
    o1[i] = f2bf((v[4 + i] - mean) * rstd * g1[i] + b1[i]);
  }
  *(u16x4*)&y[row * 512 + lane * 8] = o0;
  *(u16x4*)&y[row * 512 + lane * 8 + 4] = o1;
}

// ---------------- GEMM2: out = ln_bf16[16384,512] @ WoT[512,512]^T + bo (fp32 out) ----------------
// Grid: 1D 512, XCD-chunked decode (512 % 8 == 0).
__global__ __launch_bounds__(256) void gemm_out_kernel(const u16* __restrict__ A,
                                                       const u16* __restrict__ BT,
                                                       const float* __restrict__ bias,
                                                       float* __restrict__ out) {
  __shared__ u16 As[128 * 64];
  __shared__ u16 Bs[128 * 64];
  const int tid = threadIdx.x, lane = tid & 63, wave = tid >> 6;
  const int wr = wave >> 1, wc = wave & 1;
  const int bid = blockIdx.x;
  const int lin = (bid & 7) * 64 + (bid >> 3);
  const int m0 = (lin >> 2) * 128, n0 = (lin & 3) * 128;
  f32x4 acc[4][4] = {};
  for (int kt = 0; kt < 8; ++kt) {
    int k0 = kt * 64;
    __syncthreads();
    #pragma unroll
    for (int t = 0; t < 4; ++t) {
      int ch = wave * 4 + t;
      GLDS16(A + (size_t)(m0 + ch * 8 + (lane >> 3)) * 512 + k0 + (lane & 7) * 8, &As[ch * 512]);
      GLDS16(BT + (size_t)(n0 + ch * 8 + (lane >> 3)) * 512 + k0 + (lane & 7) * 8, &Bs[ch * 512]);
    }
    __syncthreads();
    #pragma unroll
    for (int kk = 0; kk < 2; ++kk) {
      short8 af[4], bfr[4];
      #pragma unroll
      for (int m = 0; m < 4; ++m)
        af[m] = *(const short8*)&As[(wr * 64 + m * 16 + (lane & 15)) * 64 + kk * 32 + (lane >> 4) * 8];
      #pragma unroll
      for (int n = 0; n < 4; ++n)
        bfr[n] = *(const short8*)&Bs[(wc * 64 + n * 16 + (lane & 15)) * 64 + kk * 32 + (lane >> 4) * 8];
      #pragma unroll
      for (int m = 0; m < 4; ++m)
        #pragma unroll
        for (int n = 0; n < 4; ++n)
          MFMA_BF16(acc[m][n], af[m], bfr[n]);
    }
  }
  const int row0 = m0 + wr * 64, col0 = n0 + wc * 64;
  #pragma unroll
  for (int m = 0; m < 4; ++m) {
    int row = row0 + m * 16 + (lane >> 4) * 4;
    #pragma unroll
    for (int n = 0; n < 4; ++n) {
      int col = col0 + n * 16 + (lane & 15);
      float bv = bias[col];
      #pragma unroll
      for (int i = 0; i < 4; ++i)
        out[(size_t)(row + i) * 512 + col] = acc[m][n][i] + bv;
    }
  }
}

extern "C" void kernel_launch(void* const* d_in, const int* in_sizes, int n_in,
                              void* d_out, int out_size, void* d_ws, size_t ws_size,
                              hipStream_t stream) {
  const float* x    = (const float*)d_in[0];
  const float* Wqkv = (const float*)d_in[1];
  const float* ln_g = (const float*)d_in[2];
  const float* ln_b = (const float*)d_in[3];
  const float* Wo   = (const float*)d_in[4];
  const float* bo   = (const float*)d_in[5];
  float* out = (float*)d_out;
  char* ws = (char*)d_ws;

  u16*   xbf   = (u16*)(ws);                               // 16 MB  [16384][512], reused for LN out
  u16*   wqkvt = (u16*)(ws + 16777216);                    // 1.5 MB [1536][512]
  u16*   wot   = (u16*)(ws + 18350080);                    // 0.5 MB [512][512]
  u16*   qkb   = (u16*)(ws + 18874368);                    // 32 MB  [16384][1024]
  u16*   vtb   = (u16*)(ws + 52428800);                    // 16 MB  [b*512+d][1024]
  u16*   att   = (u16*)(ws + 69206016);                    // 16 MB  [16384][512] bf16

  prep_kernel<<<4352, 256, 0, stream>>>(x, xbf, Wqkv, wqkvt, Wo, wot);
  gemm_qkv_kernel<<<1536, 256, 0, stream>>>(xbf, wqkvt, qkb, vtb);
  attn_kernel<<<512, 256, 0, stream>>>(qkb, vtb, att);
  ln_kernel<<<4096, 256, 0, stream>>>(att, ln_g, ln_b, xbf);
  gemm_out_kernel<<<512, 256, 0, stream>>>(xbf, wot, bo, out);
}